// Round 5
// baseline (575.945 us; speedup 1.0000x reference)
//
#include <hip/hip_runtime.h>

#define HID 128
#define TWO_HID 256

typedef __attribute__((ext_vector_type(8))) short short8;
typedef __attribute__((ext_vector_type(4))) float f32x4;

__device__ inline unsigned short f2b(float f){
  unsigned u = __float_as_uint(f);
  unsigned r = u + 0x7FFFu + ((u >> 16) & 1u);   // RNE
  return (unsigned short)(r >> 16);
}
__device__ inline unsigned pack2(float lo, float hi){
  return (unsigned)f2b(lo) | ((unsigned)f2b(hi) << 16);
}
__device__ inline float blo(unsigned u){ return __uint_as_float(u << 16); }
__device__ inline float bhi(unsigned u){ return __uint_as_float(u & 0xFFFF0000u); }

// ---------- CSR build ----------
__global__ void k_zero(int* __restrict__ p, int n){
  int i = blockIdx.x*blockDim.x + threadIdx.x;
  if (i < n) p[i] = 0;
}

__global__ void k_deg(const int* __restrict__ dst, int* __restrict__ deg, int E){
  int e = blockIdx.x*blockDim.x + threadIdx.x;
  if (e < E) atomicAdd(&deg[dst[e]], 1);
}

__global__ __launch_bounds__(256) void k_scan1(const int* __restrict__ deg, int* __restrict__ loc,
                                               int* __restrict__ bsum, int N){
  const int tid = threadIdx.x;
  const int i = blockIdx.x*256 + tid;
  const int lane = tid & 63, wv = tid >> 6;
  int v = (i < N) ? deg[i] : 0;
  int s = v;
  #pragma unroll
  for (int m=1; m<64; m<<=1){
    int t = __shfl_up(s, m, 64);
    if (lane >= m) s += t;
  }
  __shared__ int wsum[4];
  if (lane == 63) wsum[wv] = s;
  __syncthreads();
  if (tid == 0){
    int a = 0;
    #pragma unroll
    for (int w2=0; w2<4; w2++){ int t = wsum[w2]; wsum[w2] = a; a += t; }
    bsum[blockIdx.x] = a;
  }
  __syncthreads();
  if (i < N) loc[i] = s - v + wsum[wv];
}

__global__ __launch_bounds__(256) void k_scan2(int* __restrict__ bsum, int nb){
  const int tid = threadIdx.x;
  const int lane = tid & 63, wv = tid >> 6;
  int v = (tid < nb) ? bsum[tid] : 0;
  int s = v;
  #pragma unroll
  for (int m=1; m<64; m<<=1){
    int t = __shfl_up(s, m, 64);
    if (lane >= m) s += t;
  }
  __shared__ int wsum[4];
  if (lane == 63) wsum[wv] = s;
  __syncthreads();
  if (tid == 0){
    int a = 0;
    #pragma unroll
    for (int w2=0; w2<4; w2++){ int t = wsum[w2]; wsum[w2] = a; a += t; }
  }
  __syncthreads();
  if (tid < nb) bsum[tid] = s - v + wsum[wv];
}

__global__ __launch_bounds__(256) void k_scan3(const int* __restrict__ deg, const int* __restrict__ loc,
                                               const int* __restrict__ bsum, int* __restrict__ offs,
                                               float* __restrict__ invd, int N, int E){
  const int i = blockIdx.x*256 + threadIdx.x;
  if (i < N){
    offs[i] = loc[i] + bsum[blockIdx.x];
    int d = deg[i];
    invd[i] = 1.0f / (float)(d>1?d:1);
  }
  if (i == 0) offs[N] = E;
}

__global__ void k_fill(const int* __restrict__ src, const int* __restrict__ dst,
                       const int* __restrict__ offs, int* __restrict__ cursor,
                       int* __restrict__ ssrc, int E){
  int e = blockIdx.x*blockDim.x + threadIdx.x;
  if (e < E){
    int d = dst[e];
    int pos = offs[d] + atomicAdd(&cursor[d], 1);
    ssrc[pos] = src[e];
  }
}

// ---------- weight pre-conversion f32 -> bf16 ----------
__global__ void k_wcvt(const float* __restrict__ Wemb, const float* __restrict__ Ws,
                       unsigned short* __restrict__ Wembb, unsigned short* __restrict__ Wsb,
                       int nEmb, int nWs){
  int i = blockIdx.x*blockDim.x + threadIdx.x;
  if (i < nEmb) Wembb[i] = f2b(Wemb[i]);
  else if (i < nEmb + nWs) Wsb[i - nEmb] = f2b(Ws[i - nEmb]);
}

// ---------- input embedding: h = h0 @ Wemb^T + b  (MFMA bf16) ----------
// writes h (f32) and xb (bf16 [N][128])
__global__ __launch_bounds__(256) void k_embed(const float* __restrict__ h0, const unsigned short* __restrict__ Wb,
                                               const float* __restrict__ b, float* __restrict__ h,
                                               unsigned short* __restrict__ xb, int Ntiles){
  const int tid = threadIdx.x;
  const int w = tid >> 6, l = tid & 63;
  const int l15 = l & 15, lhi = l >> 4;
  const int cb = w * 32;

  short8 bf[2][4];
  #pragma unroll
  for (int t=0;t<2;t++){
    #pragma unroll
    for (int s=0;s<4;s++)
      bf[t][s] = *(const short8*)(Wb + (size_t)(cb + t*16 + l15)*HID + s*32 + lhi*8);
  }
  const float bias0 = b[cb + l15];
  const float bias1 = b[cb + 16 + l15];

  for (int tile = blockIdx.x; tile < Ntiles; tile += gridDim.x){
    const int row0 = tile * 16;
    short8 af[4];
    #pragma unroll
    for (int s=0;s<4;s++){
      const float* ap = h0 + (size_t)(row0 + l15)*HID + s*32 + lhi*8;
      float4 x0 = *(const float4*)ap;
      float4 x1 = *(const float4*)(ap + 4);
      short8 f;
      f[0]=(short)f2b(x0.x); f[1]=(short)f2b(x0.y); f[2]=(short)f2b(x0.z); f[3]=(short)f2b(x0.w);
      f[4]=(short)f2b(x1.x); f[5]=(short)f2b(x1.y); f[6]=(short)f2b(x1.z); f[7]=(short)f2b(x1.w);
      af[s] = f;
    }
    f32x4 acc0 = {0.f,0.f,0.f,0.f}, acc1 = {0.f,0.f,0.f,0.f};
    #pragma unroll
    for (int s=0;s<4;s++){
      acc0 = __builtin_amdgcn_mfma_f32_16x16x32_bf16(af[s], bf[0][s], acc0, 0,0,0);
      acc1 = __builtin_amdgcn_mfma_f32_16x16x32_bf16(af[s], bf[1][s], acc1, 0,0,0);
    }
    #pragma unroll
    for (int r=0;r<4;r++){
      const int row = row0 + lhi*4 + r;
      float v0 = acc0[r] + bias0;
      float v1 = acc1[r] + bias1;
      h[(size_t)row*HID + cb + l15]      = v0;
      h[(size_t)row*HID + cb + 16 + l15] = v1;
      xb[(size_t)row*HID + cb + l15]      = f2b(v0);
      xb[(size_t)row*HID + cb + 16 + l15] = f2b(v1);
    }
  }
}

// ---------- fused mean-agg + GEMM (MFMA bf16) + L2norm + relu + BN partials ----------
// Per 16-row tile: block computes c-rows into swizzled LDS, then MFMA with
// A = [xb rows (global) | c rows (LDS)], epilogue as before.
__global__ __launch_bounds__(256, 2) void k_ag(const unsigned short* __restrict__ xb,
                                               const int* __restrict__ offs, const int* __restrict__ ssrc,
                                               const float* __restrict__ invd,
                                               const unsigned short* __restrict__ Wb, const float* __restrict__ b,
                                               float* __restrict__ zb, float* __restrict__ colsums, int Ntiles){
  __shared__ __align__(16) unsigned cbuf[2][1024];   // [parity][16 rows][64 col-pairs], XOR-swizzled
  __shared__ float rowss[2][16][4];
  const int tid = threadIdx.x;
  const int w = tid >> 6, l = tid & 63;
  const int l15 = l & 15, lhi = l >> 4;
  const int cb = w * 32;
  const unsigned* xbu = (const unsigned*)xb;

  short8 bf[2][8];
  #pragma unroll
  for (int t=0;t<2;t++){
    #pragma unroll
    for (int s=0;s<8;s++)
      bf[t][s] = *(const short8*)(Wb + (size_t)(cb + t*16 + l15)*TWO_HID + s*32 + lhi*8);
  }
  const float bias0 = b[cb + l15];
  const float bias1 = b[cb + 16 + l15];
  float s1a = 0.f, s2a = 0.f, s1b = 0.f, s2b = 0.f;

  int pp = 0;
  for (int tile = blockIdx.x; tile < Ntiles; tile += gridDim.x, pp ^= 1){
    const int row0 = tile * 16;

    // --- aggregation: wave w computes c rows w*4..w*4+3 of this tile ---
    #pragma unroll
    for (int rr=0; rr<4; rr++){
      const int rl = w*4 + rr;
      const int row = row0 + rl;
      const int e0 = offs[row], e1 = offs[row+1];
      float ax = 0.f, ay = 0.f;
      int e = e0;
      for (; e + 7 < e1; e += 8){
        int a0=ssrc[e],a1=ssrc[e+1],a2=ssrc[e+2],a3=ssrc[e+3];
        int a4=ssrc[e+4],a5=ssrc[e+5],a6=ssrc[e+6],a7=ssrc[e+7];
        unsigned u0=xbu[(size_t)a0*64+l], u1=xbu[(size_t)a1*64+l];
        unsigned u2=xbu[(size_t)a2*64+l], u3=xbu[(size_t)a3*64+l];
        unsigned u4=xbu[(size_t)a4*64+l], u5=xbu[(size_t)a5*64+l];
        unsigned u6=xbu[(size_t)a6*64+l], u7=xbu[(size_t)a7*64+l];
        ax += ((blo(u0)+blo(u1))+(blo(u2)+blo(u3))) + ((blo(u4)+blo(u5))+(blo(u6)+blo(u7)));
        ay += ((bhi(u0)+bhi(u1))+(bhi(u2)+bhi(u3))) + ((bhi(u4)+bhi(u5))+(bhi(u6)+bhi(u7)));
      }
      for (; e < e1; e++){
        unsigned u = xbu[(size_t)ssrc[e]*64 + l];
        ax += blo(u); ay += bhi(u);
      }
      const float id = invd[row];
      cbuf[pp][rl*64 + (l ^ ((rl & 7) << 2))] = pack2(ax*id, ay*id);
    }
    __syncthreads();   // c tile ready

    // --- GEMM: A = [global h rows | LDS c rows] ---
    short8 af[8];
    #pragma unroll
    for (int s=0;s<4;s++)
      af[s] = *(const short8*)(xb + (size_t)(row0 + l15)*HID + s*32 + lhi*8);
    #pragma unroll
    for (int s=0;s<4;s++)
      af[4+s] = *(const short8*)&cbuf[pp][l15*64 + ((s*16 + lhi*4) ^ ((l15 & 7) << 2))];

    f32x4 acc0 = {0.f,0.f,0.f,0.f}, acc1 = {0.f,0.f,0.f,0.f};
    #pragma unroll
    for (int s=0;s<8;s++){
      acc0 = __builtin_amdgcn_mfma_f32_16x16x32_bf16(af[s], bf[0][s], acc0, 0,0,0);
      acc1 = __builtin_amdgcn_mfma_f32_16x16x32_bf16(af[s], bf[1][s], acc1, 0,0,0);
    }

    float v0[4], v1[4], pr[4];
    #pragma unroll
    for (int r=0;r<4;r++){
      v0[r] = acc0[r] + bias0;
      v1[r] = acc1[r] + bias1;
      pr[r] = v0[r]*v0[r] + v1[r]*v1[r];
    }
    #pragma unroll
    for (int m=1;m<=8;m<<=1){
      #pragma unroll
      for (int r=0;r<4;r++) pr[r] += __shfl_xor(pr[r], m, 64);
    }
    if (l15 == 0){
      #pragma unroll
      for (int r=0;r<4;r++) rowss[pp][lhi*4+r][w] = pr[r];
    }
    __syncthreads();   // rowss ready
    #pragma unroll
    for (int r=0;r<4;r++){
      const int i = lhi*4 + r;
      f32x4 q = *(const f32x4*)&rowss[pp][i][0];
      float ss = (q[0]+q[1]) + (q[2]+q[3]);
      float sc = 1.f / fmaxf(sqrtf(ss), 1e-12f);
      float z0 = fmaxf(v0[r]*sc, 0.f);
      float z1 = fmaxf(v1[r]*sc, 0.f);
      zb[(size_t)(row0+i)*HID + cb + l15]      = z0;
      zb[(size_t)(row0+i)*HID + cb + 16 + l15] = z1;
      s1a += z0; s2a += z0*z0;
      s1b += z1; s2b += z1*z1;
    }
  }
  s1a += __shfl_xor(s1a,16,64); s1a += __shfl_xor(s1a,32,64);
  s2a += __shfl_xor(s2a,16,64); s2a += __shfl_xor(s2a,32,64);
  s1b += __shfl_xor(s1b,16,64); s1b += __shfl_xor(s1b,32,64);
  s2b += __shfl_xor(s2b,16,64); s2b += __shfl_xor(s2b,32,64);
  if (lhi == 0){
    atomicAdd(&colsums[cb + l15],            s1a);
    atomicAdd(&colsums[128 + cb + l15],      s2a);
    atomicAdd(&colsums[cb + 16 + l15],       s1b);
    atomicAdd(&colsums[128 + cb + 16 + l15], s2b);
  }
}

// ---------- BN stats (inline) + apply + residual: h += z*sc + sh ; refresh bf16 mirror ----------
__global__ __launch_bounds__(256) void k_bn(const float* __restrict__ z, const float* __restrict__ colsums,
                                            const float* __restrict__ gamma, const float* __restrict__ beta,
                                            float* __restrict__ h, unsigned* __restrict__ xbu,
                                            int Nh, float invN){
  int i = blockIdx.x*blockDim.x + threadIdx.x;
  if (i >= Nh) return;
  int j = i & 63;          // float2 column-pair index
  float2 s1 = ((const float2*)colsums)[j];
  float2 s2 = ((const float2*)(colsums + 128))[j];
  float2 g  = ((const float2*)gamma)[j];
  float2 bt = ((const float2*)beta)[j];
  float mux = s1.x*invN,           muy = s1.y*invN;
  float vax = s2.x*invN - mux*mux, vay = s2.y*invN - muy*muy;
  float scx = g.x * rsqrtf(vax + 1e-5f), scy = g.y * rsqrtf(vay + 1e-5f);
  float shx = bt.x - mux*scx,            shy = bt.y - muy*scy;
  float2 zv = ((const float2*)z)[i];
  float2 hv = ((const float2*)h)[i];
  float nx = fmaf(zv.x, scx, hv.x + shx);
  float ny = fmaf(zv.y, scy, hv.y + shy);
  ((float2*)h)[i] = make_float2(nx, ny);
  xbu[i] = pack2(nx, ny);     // xb is [N][64] uints; i == node*64 + j
}

extern "C" void kernel_launch(void* const* d_in, const int* in_sizes, int n_in,
                              void* d_out, int out_size, void* d_ws, size_t ws_size,
                              hipStream_t stream){
  const float* h0   = (const float*)d_in[0];
  const int*   src  = (const int*)d_in[1];
  const int*   dst  = (const int*)d_in[2];
  const float* Wemb = (const float*)d_in[3];
  const float* bemb = (const float*)d_in[4];
  const float* Ws   = (const float*)d_in[5];
  const float* bs   = (const float*)d_in[6];
  const float* gam  = (const float*)d_in[7];
  const float* bet  = (const float*)d_in[8];
  const int N = in_sizes[0] / HID;
  const int E = in_sizes[1];
  const int Ntiles = N / 16;
  const int NB = (N + 255) / 256;
  float* h = (float*)d_out;

  char* ws = (char*)d_ws;
  size_t off = 0;
  auto alloc = [&](size_t bytes)->char*{
    char* p = ws + off;
    off = (off + bytes + 255) & ~(size_t)255;
    return p;
  };
  // deg, cursor, colsums contiguous (N*4 = 160000 is a 256-multiple) so one k_zero covers them
  int*   deg      = (int*)  alloc((size_t)N*4);
  int*   cursor   = (int*)  alloc((size_t)N*4);
  float* colsums  = (float*)alloc(4*256*4);          // per-layer BN accumulators
  int*   offs     = (int*)  alloc((size_t)(N+1)*4);
  int*   loc      = (int*)  alloc((size_t)N*4);
  int*   bsum     = (int*)  alloc((size_t)NB*4);
  float* invd     = (float*)alloc((size_t)N*4);
  int*   ssrc     = (int*)  alloc((size_t)E*4);
  unsigned short* Wembb = (unsigned short*)alloc((size_t)HID*HID*2);
  unsigned short* Wsb   = (unsigned short*)alloc((size_t)4*HID*TWO_HID*2);
  unsigned short* xb    = (unsigned short*)alloc((size_t)N*HID*2);   // bf16 h mirror
  float* zb       = (float*)alloc((size_t)N*HID*4);

  const int nEmb = HID*HID;           // 16384
  const int nWs  = 4*HID*TWO_HID;     // 131072

  hipLaunchKernelGGL(k_zero,  dim3((2*N+1024+255)/256), dim3(256), 0, stream, deg, 2*N+1024);
  hipLaunchKernelGGL(k_deg,   dim3((E+255)/256),   dim3(256), 0, stream, dst, deg, E);
  hipLaunchKernelGGL(k_scan1, dim3(NB),  dim3(256), 0, stream, deg, loc, bsum, N);
  hipLaunchKernelGGL(k_scan2, dim3(1),   dim3(256), 0, stream, bsum, NB);
  hipLaunchKernelGGL(k_scan3, dim3(NB),  dim3(256), 0, stream, deg, loc, bsum, offs, invd, N, E);
  hipLaunchKernelGGL(k_fill,  dim3((E+255)/256),   dim3(256), 0, stream, src, dst, offs, cursor, ssrc, E);
  hipLaunchKernelGGL(k_wcvt,  dim3((nEmb+nWs+255)/256), dim3(256), 0, stream, Wemb, Ws, Wembb, Wsb, nEmb, nWs);

  hipLaunchKernelGGL(k_embed, dim3(512), dim3(256), 0, stream, h0, Wembb, bemb, h, xb, Ntiles);

  for (int l=0;l<4;l++){
    hipLaunchKernelGGL(k_ag, dim3(512), dim3(256), 0, stream,
                       xb, offs, ssrc, invd,
                       Wsb + (size_t)l*HID*TWO_HID, bs + (size_t)l*HID,
                       zb, colsums + (size_t)l*256, Ntiles);
    hipLaunchKernelGGL(k_bn, dim3((N*64+255)/256), dim3(256), 0, stream,
                       zb, colsums + (size_t)l*256, gam + (size_t)l*HID, bet + (size_t)l*HID,
                       h, (unsigned*)xb, N*64, 1.0f/(float)N);
  }
}

// Round 6
// 440.143 us; speedup vs baseline: 1.3085x; 1.3085x over previous
//
#include <hip/hip_runtime.h>

#define HID 128
#define TWO_HID 256

typedef __attribute__((ext_vector_type(8))) short short8;
typedef __attribute__((ext_vector_type(4))) float f32x4;

__device__ inline unsigned short f2b(float f){
  unsigned u = __float_as_uint(f);
  unsigned r = u + 0x7FFFu + ((u >> 16) & 1u);   // RNE
  return (unsigned short)(r >> 16);
}
__device__ inline unsigned pack2(float lo, float hi){
  return (unsigned)f2b(lo) | ((unsigned)f2b(hi) << 16);
}
__device__ inline float blo(unsigned u){ return __uint_as_float(u << 16); }
__device__ inline float bhi(unsigned u){ return __uint_as_float(u & 0xFFFF0000u); }

// ---------- CSR build ----------
__global__ void k_zero(int* __restrict__ p, int n){
  int i = blockIdx.x*blockDim.x + threadIdx.x;
  if (i < n) p[i] = 0;
}

__global__ void k_deg(const int* __restrict__ dst, int* __restrict__ deg, int E){
  int e = blockIdx.x*blockDim.x + threadIdx.x;
  if (e < E) atomicAdd(&deg[dst[e]], 1);
}

__global__ __launch_bounds__(256) void k_scan1(const int* __restrict__ deg, int* __restrict__ loc,
                                               int* __restrict__ bsum, int N){
  const int tid = threadIdx.x;
  const int i = blockIdx.x*256 + tid;
  const int lane = tid & 63, wv = tid >> 6;
  int v = (i < N) ? deg[i] : 0;
  int s = v;
  #pragma unroll
  for (int m=1; m<64; m<<=1){
    int t = __shfl_up(s, m, 64);
    if (lane >= m) s += t;
  }
  __shared__ int wsum[4];
  if (lane == 63) wsum[wv] = s;
  __syncthreads();
  if (tid == 0){
    int a = 0;
    #pragma unroll
    for (int w2=0; w2<4; w2++){ int t = wsum[w2]; wsum[w2] = a; a += t; }
    bsum[blockIdx.x] = a;
  }
  __syncthreads();
  if (i < N) loc[i] = s - v + wsum[wv];
}

__global__ __launch_bounds__(256) void k_scan2(int* __restrict__ bsum, int nb){
  const int tid = threadIdx.x;
  const int lane = tid & 63, wv = tid >> 6;
  int v = (tid < nb) ? bsum[tid] : 0;
  int s = v;
  #pragma unroll
  for (int m=1; m<64; m<<=1){
    int t = __shfl_up(s, m, 64);
    if (lane >= m) s += t;
  }
  __shared__ int wsum[4];
  if (lane == 63) wsum[wv] = s;
  __syncthreads();
  if (tid == 0){
    int a = 0;
    #pragma unroll
    for (int w2=0; w2<4; w2++){ int t = wsum[w2]; wsum[w2] = a; a += t; }
  }
  __syncthreads();
  if (tid < nb) bsum[tid] = s - v + wsum[wv];
}

__global__ __launch_bounds__(256) void k_scan3(const int* __restrict__ deg, const int* __restrict__ loc,
                                               const int* __restrict__ bsum, int* __restrict__ offs,
                                               float* __restrict__ invd, int N, int E){
  const int i = blockIdx.x*256 + threadIdx.x;
  if (i < N){
    offs[i] = loc[i] + bsum[blockIdx.x];
    int d = deg[i];
    invd[i] = 1.0f / (float)(d>1?d:1);
  }
  if (i == 0) offs[N] = E;
}

__global__ void k_fill(const int* __restrict__ src, const int* __restrict__ dst,
                       const int* __restrict__ offs, int* __restrict__ cursor,
                       int* __restrict__ ssrc, int E){
  int e = blockIdx.x*blockDim.x + threadIdx.x;
  if (e < E){
    int d = dst[e];
    int pos = offs[d] + atomicAdd(&cursor[d], 1);
    ssrc[pos] = src[e];
  }
}

// ---------- weight pre-conversion f32 -> bf16 ----------
__global__ void k_wcvt(const float* __restrict__ Wemb, const float* __restrict__ Ws,
                       unsigned short* __restrict__ Wembb, unsigned short* __restrict__ Wsb,
                       int nEmb, int nWs){
  int i = blockIdx.x*blockDim.x + threadIdx.x;
  if (i < nEmb) Wembb[i] = f2b(Wemb[i]);
  else if (i < nEmb + nWs) Wsb[i - nEmb] = f2b(Ws[i - nEmb]);
}

// ---------- input embedding: h = h0 @ Wemb^T + b  (MFMA bf16) ----------
// writes h (f32) and xh (bf16 [N][128])
__global__ __launch_bounds__(256) void k_embed(const float* __restrict__ h0, const unsigned short* __restrict__ Wb,
                                               const float* __restrict__ b, float* __restrict__ h,
                                               unsigned short* __restrict__ xh, int Ntiles){
  const int tid = threadIdx.x;
  const int w = tid >> 6, l = tid & 63;
  const int l15 = l & 15, lhi = l >> 4;
  const int cb = w * 32;

  short8 bf[2][4];
  #pragma unroll
  for (int t=0;t<2;t++){
    #pragma unroll
    for (int s=0;s<4;s++)
      bf[t][s] = *(const short8*)(Wb + (size_t)(cb + t*16 + l15)*HID + s*32 + lhi*8);
  }
  const float bias0 = b[cb + l15];
  const float bias1 = b[cb + 16 + l15];

  for (int tile = blockIdx.x; tile < Ntiles; tile += gridDim.x){
    const int row0 = tile * 16;
    short8 af[4];
    #pragma unroll
    for (int s=0;s<4;s++){
      const float* ap = h0 + (size_t)(row0 + l15)*HID + s*32 + lhi*8;
      float4 x0 = *(const float4*)ap;
      float4 x1 = *(const float4*)(ap + 4);
      short8 f;
      f[0]=(short)f2b(x0.x); f[1]=(short)f2b(x0.y); f[2]=(short)f2b(x0.z); f[3]=(short)f2b(x0.w);
      f[4]=(short)f2b(x1.x); f[5]=(short)f2b(x1.y); f[6]=(short)f2b(x1.z); f[7]=(short)f2b(x1.w);
      af[s] = f;
    }
    f32x4 acc0 = {0.f,0.f,0.f,0.f}, acc1 = {0.f,0.f,0.f,0.f};
    #pragma unroll
    for (int s=0;s<4;s++){
      acc0 = __builtin_amdgcn_mfma_f32_16x16x32_bf16(af[s], bf[0][s], acc0, 0,0,0);
      acc1 = __builtin_amdgcn_mfma_f32_16x16x32_bf16(af[s], bf[1][s], acc1, 0,0,0);
    }
    #pragma unroll
    for (int r=0;r<4;r++){
      const int row = row0 + lhi*4 + r;
      float v0 = acc0[r] + bias0;
      float v1 = acc1[r] + bias1;
      h[(size_t)row*HID + cb + l15]      = v0;
      h[(size_t)row*HID + cb + 16 + l15] = v1;
      xh[(size_t)row*HID + cb + l15]      = f2b(v0);
      xh[(size_t)row*HID + cb + 16 + l15] = f2b(v1);
    }
  }
}

// ---------- mean aggregation: cb[v] = mean of xh[src] (bf16 -> bf16) ----------
// one wave per node, 10000 blocks: gather latency hidden by block oversubscription
__global__ __launch_bounds__(256) void k_agg(const unsigned* __restrict__ xhu, const int* __restrict__ offs,
                                             const int* __restrict__ ssrc, const float* __restrict__ invd,
                                             unsigned* __restrict__ cbu, int N){
  int gid = blockIdx.x*blockDim.x + threadIdx.x;
  int node = gid >> 6;
  int lane = gid & 63;     // uint = 2 features
  if (node >= N) return;
  int e0 = offs[node], e1 = offs[node+1];
  float ax = 0.f, ay = 0.f;
  int e = e0;
  for (; e + 7 < e1; e += 8){
    int a0=ssrc[e],a1=ssrc[e+1],a2=ssrc[e+2],a3=ssrc[e+3];
    int a4=ssrc[e+4],a5=ssrc[e+5],a6=ssrc[e+6],a7=ssrc[e+7];
    unsigned u0=xhu[(size_t)a0*64+lane], u1=xhu[(size_t)a1*64+lane];
    unsigned u2=xhu[(size_t)a2*64+lane], u3=xhu[(size_t)a3*64+lane];
    unsigned u4=xhu[(size_t)a4*64+lane], u5=xhu[(size_t)a5*64+lane];
    unsigned u6=xhu[(size_t)a6*64+lane], u7=xhu[(size_t)a7*64+lane];
    ax += ((blo(u0)+blo(u1))+(blo(u2)+blo(u3))) + ((blo(u4)+blo(u5))+(blo(u6)+blo(u7)));
    ay += ((bhi(u0)+bhi(u1))+(bhi(u2)+bhi(u3))) + ((bhi(u4)+bhi(u5))+(bhi(u6)+bhi(u7)));
  }
  for (; e + 1 < e1; e += 2){
    unsigned u0 = xhu[(size_t)ssrc[e]*64 + lane];
    unsigned u1 = xhu[(size_t)ssrc[e+1]*64 + lane];
    ax += blo(u0) + blo(u1);
    ay += bhi(u0) + bhi(u1);
  }
  if (e < e1){
    unsigned u0 = xhu[(size_t)ssrc[e]*64 + lane];
    ax += blo(u0); ay += bhi(u0);
  }
  float id = invd[node];
  cbu[(size_t)node*64 + lane] = pack2(ax*id, ay*id);
}

// ---------- layer GEMM (MFMA bf16) + L2norm + relu + BN partial sums ----------
// A = [xh row | cb row], both bf16 global streams
__global__ __launch_bounds__(256) void k_gemm(const unsigned short* __restrict__ xh,
                                              const unsigned short* __restrict__ cbt,
                                              const unsigned short* __restrict__ Wb, const float* __restrict__ b,
                                              float* __restrict__ zb, float* __restrict__ colsums, int Ntiles){
  __shared__ float rowss[2][16][4];
  const int tid = threadIdx.x;
  const int w = tid >> 6, l = tid & 63;
  const int l15 = l & 15, lhi = l >> 4;
  const int cb = w * 32;

  short8 bf[2][8];
  #pragma unroll
  for (int t=0;t<2;t++){
    #pragma unroll
    for (int s=0;s<8;s++)
      bf[t][s] = *(const short8*)(Wb + (size_t)(cb + t*16 + l15)*TWO_HID + s*32 + lhi*8);
  }
  const float bias0 = b[cb + l15];
  const float bias1 = b[cb + 16 + l15];
  float s1a = 0.f, s2a = 0.f, s1b = 0.f, s2b = 0.f;

  int pp = 0;
  for (int tile = blockIdx.x; tile < Ntiles; tile += gridDim.x, pp ^= 1){
    const int row0 = tile * 16;
    short8 af[8];
    #pragma unroll
    for (int s=0;s<4;s++)
      af[s] = *(const short8*)(xh + (size_t)(row0 + l15)*HID + s*32 + lhi*8);
    #pragma unroll
    for (int s=0;s<4;s++)
      af[4+s] = *(const short8*)(cbt + (size_t)(row0 + l15)*HID + s*32 + lhi*8);

    f32x4 acc0 = {0.f,0.f,0.f,0.f}, acc1 = {0.f,0.f,0.f,0.f};
    #pragma unroll
    for (int s=0;s<8;s++){
      acc0 = __builtin_amdgcn_mfma_f32_16x16x32_bf16(af[s], bf[0][s], acc0, 0,0,0);
      acc1 = __builtin_amdgcn_mfma_f32_16x16x32_bf16(af[s], bf[1][s], acc1, 0,0,0);
    }

    float v0[4], v1[4], pr[4];
    #pragma unroll
    for (int r=0;r<4;r++){
      v0[r] = acc0[r] + bias0;
      v1[r] = acc1[r] + bias1;
      pr[r] = v0[r]*v0[r] + v1[r]*v1[r];
    }
    #pragma unroll
    for (int m=1;m<=8;m<<=1){
      #pragma unroll
      for (int r=0;r<4;r++) pr[r] += __shfl_xor(pr[r], m, 64);
    }
    if (l15 == 0){
      #pragma unroll
      for (int r=0;r<4;r++) rowss[pp][lhi*4+r][w] = pr[r];
    }
    __syncthreads();
    #pragma unroll
    for (int r=0;r<4;r++){
      const int i = lhi*4 + r;
      f32x4 q = *(const f32x4*)&rowss[pp][i][0];
      float ss = (q[0]+q[1]) + (q[2]+q[3]);
      float sc = 1.f / fmaxf(sqrtf(ss), 1e-12f);
      float z0 = fmaxf(v0[r]*sc, 0.f);
      float z1 = fmaxf(v1[r]*sc, 0.f);
      zb[(size_t)(row0+i)*HID + cb + l15]      = z0;
      zb[(size_t)(row0+i)*HID + cb + 16 + l15] = z1;
      s1a += z0; s2a += z0*z0;
      s1b += z1; s2b += z1*z1;
    }
  }
  s1a += __shfl_xor(s1a,16,64); s1a += __shfl_xor(s1a,32,64);
  s2a += __shfl_xor(s2a,16,64); s2a += __shfl_xor(s2a,32,64);
  s1b += __shfl_xor(s1b,16,64); s1b += __shfl_xor(s1b,32,64);
  s2b += __shfl_xor(s2b,16,64); s2b += __shfl_xor(s2b,32,64);
  if (lhi == 0){
    atomicAdd(&colsums[cb + l15],            s1a);
    atomicAdd(&colsums[128 + cb + l15],      s2a);
    atomicAdd(&colsums[cb + 16 + l15],       s1b);
    atomicAdd(&colsums[128 + cb + 16 + l15], s2b);
  }
}

// ---------- BN stats (inline) + apply + residual: h += z*sc + sh ; refresh bf16 mirror ----------
__global__ __launch_bounds__(256) void k_bn(const float* __restrict__ z, const float* __restrict__ colsums,
                                            const float* __restrict__ gamma, const float* __restrict__ beta,
                                            float* __restrict__ h, unsigned* __restrict__ xhu,
                                            int Nh, float invN){
  int i = blockIdx.x*blockDim.x + threadIdx.x;
  if (i >= Nh) return;
  int j = i & 63;          // float2 column-pair index
  float2 s1 = ((const float2*)colsums)[j];
  float2 s2 = ((const float2*)(colsums + 128))[j];
  float2 g  = ((const float2*)gamma)[j];
  float2 bt = ((const float2*)beta)[j];
  float mux = s1.x*invN,           muy = s1.y*invN;
  float vax = s2.x*invN - mux*mux, vay = s2.y*invN - muy*muy;
  float scx = g.x * rsqrtf(vax + 1e-5f), scy = g.y * rsqrtf(vay + 1e-5f);
  float shx = bt.x - mux*scx,            shy = bt.y - muy*scy;
  float2 zv = ((const float2*)z)[i];
  float2 hv = ((const float2*)h)[i];
  float nx = fmaf(zv.x, scx, hv.x + shx);
  float ny = fmaf(zv.y, scy, hv.y + shy);
  ((float2*)h)[i] = make_float2(nx, ny);
  xhu[i] = pack2(nx, ny);     // xh is [N][64] uints; i == node*64 + j
}

extern "C" void kernel_launch(void* const* d_in, const int* in_sizes, int n_in,
                              void* d_out, int out_size, void* d_ws, size_t ws_size,
                              hipStream_t stream){
  const float* h0   = (const float*)d_in[0];
  const int*   src  = (const int*)d_in[1];
  const int*   dst  = (const int*)d_in[2];
  const float* Wemb = (const float*)d_in[3];
  const float* bemb = (const float*)d_in[4];
  const float* Ws   = (const float*)d_in[5];
  const float* bs   = (const float*)d_in[6];
  const float* gam  = (const float*)d_in[7];
  const float* bet  = (const float*)d_in[8];
  const int N = in_sizes[0] / HID;
  const int E = in_sizes[1];
  const int Ntiles = N / 16;
  const int NB = (N + 255) / 256;
  float* h = (float*)d_out;

  char* ws = (char*)d_ws;
  size_t off = 0;
  auto alloc = [&](size_t bytes)->char*{
    char* p = ws + off;
    off = (off + bytes + 255) & ~(size_t)255;
    return p;
  };
  // deg, cursor, colsums contiguous (N*4 = 160000 is a 256-multiple) so one k_zero covers them
  int*   deg      = (int*)  alloc((size_t)N*4);
  int*   cursor   = (int*)  alloc((size_t)N*4);
  float* colsums  = (float*)alloc(4*256*4);          // per-layer BN accumulators
  int*   offs     = (int*)  alloc((size_t)(N+1)*4);
  int*   loc      = (int*)  alloc((size_t)N*4);
  int*   bsum     = (int*)  alloc((size_t)NB*4);
  float* invd     = (float*)alloc((size_t)N*4);
  int*   ssrc     = (int*)  alloc((size_t)E*4);
  unsigned short* Wembb = (unsigned short*)alloc((size_t)HID*HID*2);
  unsigned short* Wsb   = (unsigned short*)alloc((size_t)4*HID*TWO_HID*2);
  unsigned short* xh    = (unsigned short*)alloc((size_t)N*HID*2);   // bf16 h mirror
  unsigned short* cbt   = (unsigned short*)alloc((size_t)N*HID*2);   // bf16 aggregate
  float* zb       = (float*)alloc((size_t)N*HID*4);

  const int nEmb = HID*HID;           // 16384
  const int nWs  = 4*HID*TWO_HID;     // 131072

  hipLaunchKernelGGL(k_zero,  dim3((2*N+1024+255)/256), dim3(256), 0, stream, deg, 2*N+1024);
  hipLaunchKernelGGL(k_deg,   dim3((E+255)/256),   dim3(256), 0, stream, dst, deg, E);
  hipLaunchKernelGGL(k_scan1, dim3(NB),  dim3(256), 0, stream, deg, loc, bsum, N);
  hipLaunchKernelGGL(k_scan2, dim3(1),   dim3(256), 0, stream, bsum, NB);
  hipLaunchKernelGGL(k_scan3, dim3(NB),  dim3(256), 0, stream, deg, loc, bsum, offs, invd, N, E);
  hipLaunchKernelGGL(k_fill,  dim3((E+255)/256),   dim3(256), 0, stream, src, dst, offs, cursor, ssrc, E);
  hipLaunchKernelGGL(k_wcvt,  dim3((nEmb+nWs+255)/256), dim3(256), 0, stream, Wemb, Ws, Wembb, Wsb, nEmb, nWs);

  hipLaunchKernelGGL(k_embed, dim3(512), dim3(256), 0, stream, h0, Wembb, bemb, h, xh, Ntiles);

  for (int l=0;l<4;l++){
    hipLaunchKernelGGL(k_agg, dim3((N*64+255)/256), dim3(256), 0, stream,
                       (const unsigned*)xh, offs, ssrc, invd, (unsigned*)cbt, N);
    hipLaunchKernelGGL(k_gemm, dim3(512), dim3(256), 0, stream,
                       xh, cbt, Wsb + (size_t)l*HID*TWO_HID, bs + (size_t)l*HID,
                       zb, colsums + (size_t)l*256, Ntiles);
    hipLaunchKernelGGL(k_bn, dim3((N*64+255)/256), dim3(256), 0, stream,
                       zb, colsums + (size_t)l*256, gam + (size_t)l*HID, bet + (size_t)l*HID,
                       h, (unsigned*)xh, N*64, 1.0f/(float)N);
  }
}